// Round 6
// baseline (81.533 us; speedup 1.0000x reference)
//
#include <hip/hip_runtime.h>
#include <stdint.h>

#define WIN 8
#define DEG 16
#define ORDER 500
#define STEPS_C 50
#define T1 51          // STEPS+1
#define FRD 15         // feature rows = 2*WIN-1
#define BLOCK 256
#define GPW 8          // lanes per walker
#define WPB 32         // walkers per block
#define BPG 16         // blocks per graph = ceil(500/32)
#define NI 8           // adj_bits words per node
#define NSTRS 52       // nodes/eidx LDS row stride (elements)
#define MSTR 17        // mask LDS row stride (u64)
#define ABSTR 9        // adj_bits LDS row stride (ints, padded 8->9)

__global__ __launch_bounds__(256)
void walker_kernel(const int* __restrict__ adj_nodes,
                   const int* __restrict__ adj_bits,
                   const int* __restrict__ choices,
                   float* __restrict__ out, int N)
{
    __shared__ unsigned short g_adj[ORDER * DEG];          // 16000 B (local ids)
    __shared__ int g_bits[ORDER * ABSTR];                  // 18000 B
    __shared__ int choice_lds[STEPS_C * WPB];              // 6400 B
    __shared__ unsigned short nodes_l[WPB * NSTRS];        // 3328 B (local ids)
    __shared__ unsigned char  eidx_l[WPB * NSTRS];         // 1664 B
    __shared__ unsigned long long mask_lds[WPB * MSTR];    // 4352 B
    // total ~49.7 KB -> 3 blocks/CU

    const int tid   = threadIdx.x;
    const int lane  = tid & 63;
    const int r     = tid & (GPW - 1);        // window-slot role
    const int g     = tid >> 3;               // walker group in block [0,32)
    const int graph = blockIdx.x >> 4;        // / BPG
    const int lb    = blockIdx.x & (BPG - 1);
    const int gbase = graph * ORDER;
    const int lstart = lb * WPB + g;          // local walker id within graph
    const bool act  = (lstart < ORDER);
    const int wbaseN = gbase + lb * WPB;      // first walker id of this block

    float* out0 = out;                                // walk_nodes N x 51
    float* out1 = out + (size_t)N * T1;               // walk_edges N x 50
    float* out2 = out1 + (size_t)N * STEPS_C;         // walk_x     N x 15 x 51

    // ---- stage graph tables + this block's choices into LDS (coalesced) ----
    {
        const int2* src = reinterpret_cast<const int2*>(adj_nodes + (size_t)gbase * DEG);
        unsigned* dst = reinterpret_cast<unsigned*>(g_adj);
        for (int c = tid; c < ORDER * DEG / 2; c += BLOCK) {
            const int2 v = src[c];
            dst[c] = (unsigned)(v.x - gbase) | ((unsigned)(v.y - gbase) << 16);
        }
        const int4* srcb = reinterpret_cast<const int4*>(adj_bits + (size_t)gbase * NI);
        for (int c = tid; c < ORDER * NI / 4; c += BLOCK) {
            const int4 v = srcb[c];
            const int row = c >> 1;
            const int qb  = (c & 1) << 2;
            g_bits[row * ABSTR + qb + 0] = v.x;
            g_bits[row * ABSTR + qb + 1] = v.y;
            g_bits[row * ABSTR + qb + 2] = v.z;
            g_bits[row * ABSTR + qb + 3] = v.w;
        }
        for (int c = tid; c < STEPS_C * WPB; c += BLOCK) {
            const int t  = c >> 5;            // / WPB
            const int gg = c & (WPB - 1);
            int src_i = wbaseN + gg;
            if (src_i >= N) src_i = N - 1;    // clamp (last block of last graph)
            choice_lds[c] = choices[(size_t)t * N + src_i];
        }
    }
    __syncthreads();

    unsigned long long idm = 0ull;   // id-row r
    unsigned long long adm = 0ull;   // adj-row r (r<7)

    if (act) {
        // window slot r content (local ids); slot7 = cur
        int wsel = (r == 7) ? lstart : 0;
        int cur  = lstart;            // w[7]
        int prev = -1;                // w[6], invalid until t>=1

        if (r == 0) nodes_l[g * NSTRS] = (unsigned short)lstart;

        for (int t = 0; t < STEPS_C; t++) {
            const int ch = choice_lds[t * WPB + g];   // broadcast within group

            // deg==16 pow2: floored mod == AND (valid for negatives)
            const int e = ch & (DEG - 1);
            int r15 = ch % (DEG - 1); if (r15 < 0) r15 += (DEG - 1);
            const int e2 = (e + 1 + r15) & (DEG - 1);

            // both candidate neighbors from LDS (same addr across group -> broadcast)
            const int n1 = g_adj[cur * DEG + e];
            const int n2 = g_adj[cur * DEG + e2];

            const bool bt = (t >= 1) && (n1 == prev);
            const int nn = bt ? n2 : n1;              // local id
            const int ee = bt ? e2 : e;               // edge index in [0,16)

            // cid == local id directly
            const unsigned q  = (unsigned)nn / 63u;
            const unsigned rr = (unsigned)nn - q * 63u;
            const unsigned long long bitpos = 1ull << (t + 1);
            const bool vk = (r + t) >= (WIN - 1);

            if (vk && (wsel == nn)) idm |= bitpos;

            // adj row r: bit of adj_bits[w[r]] at new node's id (int32-truncated,
            // saturating shift). lane r=7 load is a harmless dup.
            const int word = g_bits[wsel * ABSTR + q];
            const unsigned s = rr > 31u ? 31u : rr;
            if (vk && (r < 7) && ((word >> s) & 1)) adm |= bitpos;

            // window shift: slot r <- old slot r+1; slot7 <- nn
            const int up = __shfl(wsel, (lane & ~7) | ((r < 7) ? (r + 1) : 7));
            wsel = (r == 7) ? nn : up;
            prev = cur;
            cur  = nn;

            if (r == 0) nodes_l[g * NSTRS + t + 1] = (unsigned short)nn;
            if (r == 1) eidx_l[g * NSTRS + t]      = (unsigned char)ee;
        }

        mask_lds[g * MSTR + r] = idm;
        if (r < 7) mask_lds[g * MSTR + 8 + r] = adm;
    }
    __syncthreads();

    // -------- store phase: coalesced float4 streams --------
    int nvalid = ORDER - lb * WPB;
    if (nvalid > WPB) nvalid = WPB;     // 32, or 20 in last block of graph

    // out0: nodes [wl][51] = gbase + local
    {
        float* dst = out0 + (size_t)wbaseN * T1;
        const unsigned nch = (unsigned)(nvalid * T1) >> 2;
        for (unsigned c = tid; c < nch; c += BLOCK) {
            const unsigned f0 = c << 2;
            float vv[4];
#pragma unroll
            for (int u = 0; u < 4; u++) {
                const unsigned idx = f0 + u;
                const unsigned wl = idx / (unsigned)T1;
                const unsigned t  = idx - wl * (unsigned)T1;
                vv[u] = (float)(gbase + (int)nodes_l[wl * NSTRS + t]);
            }
            float4 v; v.x = vv[0]; v.y = vv[1]; v.z = vv[2]; v.w = vv[3];
            *reinterpret_cast<float4*>(dst + f0) = v;
        }
    }
    // out1: edges [wl][50] = (gbase + cur_t)*16 + eidx_t ; cur_t = nodes[t]
    {
        float* dst = out1 + (size_t)wbaseN * STEPS_C;
        const unsigned nch = (unsigned)(nvalid * STEPS_C) >> 2;
        for (unsigned c = tid; c < nch; c += BLOCK) {
            const unsigned f0 = c << 2;
            float vv[4];
#pragma unroll
            for (int u = 0; u < 4; u++) {
                const unsigned idx = f0 + u;
                const unsigned wl = idx / (unsigned)STEPS_C;
                const unsigned t  = idx - wl * (unsigned)STEPS_C;
                const int cur = (int)nodes_l[wl * NSTRS + t];
                const int ei  = (int)eidx_l[wl * NSTRS + t];
                vv[u] = (float)(((gbase + cur) << 4) + ei);   // < 2^24, exact
            }
            float4 v; v.x = vv[0]; v.y = vv[1]; v.z = vv[2]; v.w = vv[3];
            *reinterpret_cast<float4*>(dst + f0) = v;
        }
    }
    // out2: expand bitmasks -> float 0/1, [wl][j<15][t<51]
    {
        float* dst = out2 + (size_t)wbaseN * (FRD * T1);
        const unsigned nch = (unsigned)(nvalid * (FRD * T1)) >> 2;
        for (unsigned c = tid; c < nch; c += BLOCK) {
            const unsigned f0 = c << 2;
            unsigned uu = f0 / (unsigned)T1;
            unsigned t  = f0 - uu * (unsigned)T1;
            unsigned wl = uu / (unsigned)FRD;
            unsigned j  = uu - wl * (unsigned)FRD;
            float vv[4];
#pragma unroll
            for (int u = 0; u < 4; u++) {
                const unsigned long long m = mask_lds[wl * MSTR + j];
                vv[u] = ((m >> t) & 1ull) ? 1.0f : 0.0f;
                t++;
                if (t == T1) { t = 0; j++; if (j == FRD) { j = 0; wl++; } }
            }
            float4 v; v.x = vv[0]; v.y = vv[1]; v.z = vv[2]; v.w = vv[3];
            *reinterpret_cast<float4*>(dst + f0) = v;
        }
    }
}

extern "C" void kernel_launch(void* const* d_in, const int* in_sizes, int n_in,
                              void* d_out, int out_size, void* d_ws, size_t ws_size,
                              hipStream_t stream) {
    const int N = in_sizes[3];               // 50000
    const int num_graphs = N / ORDER;        // 100

    const int grid = num_graphs * BPG;       // 1600

    walker_kernel<<<grid, BLOCK, 0, stream>>>(
        (const int*)d_in[0], (const int*)d_in[4], (const int*)d_in[5],
        (float*)d_out, N);
}

// Round 7
// 77.132 us; speedup vs baseline: 1.0571x; 1.0571x over previous
//
#include <hip/hip_runtime.h>
#include <stdint.h>

#define WIN 8
#define DEG 16
#define ORDER 500
#define STEPS_C 50
#define T1 51          // STEPS+1
#define FRD 15         // feature rows = 2*WIN-1
#define NI 8           // adj_bits words per node

// ============================================================
// Two-kernel path. ws layout (SoA, coalesced in both kernels):
//   masks u64[15][N]  | nodes u16[51][N] | eidx u8[50][N]
// ============================================================

__global__ __launch_bounds__(256)
void walk_kernel(const int* __restrict__ adj_nodes,
                 const int* __restrict__ adj_bits,
                 const int* __restrict__ choices,
                 unsigned long long* __restrict__ masks_ws,  // [15][N]
                 unsigned short* __restrict__ nodes_ws,      // [51][N]
                 unsigned char* __restrict__ eidx_ws,        // [50][N]
                 int N)
{
    __shared__ unsigned short g_adj[ORDER * DEG];   // 16000 B (local ids)
    __shared__ int g_bits[ORDER * NI];              // 16000 B (unpadded; banks uniform)

    const int tid   = threadIdx.x;
    const int graph = blockIdx.x >> 1;
    const int lb    = blockIdx.x & 1;
    const int gbase = graph * ORDER;
    const int lstart = lb * 250 + tid;        // local walker id
    const bool act  = (tid < 250);            // 250 walkers per block
    const int wi    = gbase + lstart;
    const int wild  = act ? wi : gbase;       // safe load index

    // ---- stage graph tables into LDS (coalesced) ----
    {
        const int4* src = reinterpret_cast<const int4*>(adj_nodes + (size_t)gbase * DEG);
        unsigned* dst = reinterpret_cast<unsigned*>(g_adj);
        for (int c = tid; c < ORDER * DEG / 4; c += 256) {
            const int4 v = src[c];
            dst[2 * c + 0] = (unsigned)(v.x - gbase) | ((unsigned)(v.y - gbase) << 16);
            dst[2 * c + 1] = (unsigned)(v.z - gbase) | ((unsigned)(v.w - gbase) << 16);
        }
        int4* db = reinterpret_cast<int4*>(g_bits);
        const int4* sb = reinterpret_cast<const int4*>(adj_bits + (size_t)gbase * NI);
        for (int c = tid; c < ORDER * NI / 4; c += 256) db[c] = sb[c];
    }
    __syncthreads();

    int w[WIN];
    unsigned long long idm[WIN];
    unsigned long long adm[WIN - 1];
#pragma unroll
    for (int k = 0; k < WIN; k++) { w[k] = 0; idm[k] = 0ull; }
#pragma unroll
    for (int k = 0; k < WIN - 1; k++) adm[k] = 0ull;
    w[7] = act ? lstart : 0;

    if (act) nodes_ws[wi] = (unsigned short)lstart;   // row t=0

    // depth-4 rolling register prefetch of choices (coalesced)
    int c0 = choices[wild];
    int c1 = choices[(size_t)1 * N + wild];
    int c2 = choices[(size_t)2 * N + wild];
    int c3 = choices[(size_t)3 * N + wild];

    for (int t = 0; t < STEPS_C; t++) {
        const int ch = c0;
        c0 = c1; c1 = c2; c2 = c3;
        c3 = (t + 4 < STEPS_C) ? choices[(size_t)(t + 4) * N + wild] : 0;

        // deg==16 pow2: floored mod == AND (valid for negatives)
        const int e = ch & (DEG - 1);
        int r15 = ch % (DEG - 1); if (r15 < 0) r15 += (DEG - 1);
        const int e2 = (e + 1 + r15) & (DEG - 1);

        const int cur = w[7];
        const int n1 = g_adj[cur * DEG + e];
        const int n2 = g_adj[cur * DEG + e2];

        const bool bt = (t >= 1) && (n1 == w[6]);
        const int nn = bt ? n2 : n1;        // local id
        const int ee = bt ? e2 : e;         // edge index [0,16)

        // cid == local id directly (node_id closed form)
        const unsigned q  = (unsigned)nn / 63u;
        const unsigned rr = (unsigned)nn - q * 63u;
        const unsigned s  = rr > 31u ? 31u : rr;    // int32 saturating shift
        const unsigned long long bitpos = 1ull << (t + 1);

#pragma unroll
        for (int k = 0; k < WIN; k++) {
            const bool vk = (k + t) >= (WIN - 1);
            if (vk && (w[k] == nn)) idm[k] |= bitpos;
        }
#pragma unroll
        for (int k = 0; k < WIN - 1; k++) {
            const bool vk = (k + t) >= (WIN - 1);
            const int word = g_bits[w[k] * NI + q];
            if (vk && ((word >> s) & 1)) adm[k] |= bitpos;
        }

#pragma unroll
        for (int k = 0; k < WIN - 1; k++) w[k] = w[k + 1];
        w[7] = nn;

        if (act) {
            nodes_ws[(size_t)(t + 1) * N + wi] = (unsigned short)nn;
            eidx_ws[(size_t)t * N + wi]        = (unsigned char)ee;
        }
    }

    if (act) {
#pragma unroll
        for (int k = 0; k < WIN; k++)
            masks_ws[(size_t)k * N + wi] = idm[k];
#pragma unroll
        for (int k = 0; k < WIN - 1; k++)
            masks_ws[(size_t)(8 + k) * N + wi] = adm[k];
    }
}

__global__ __launch_bounds__(256)
void expand_kernel(const unsigned long long* __restrict__ masks_ws,
                   const unsigned short* __restrict__ nodes_ws,
                   const unsigned char* __restrict__ eidx_ws,
                   float* __restrict__ out, int N)
{
    const unsigned A = (unsigned)N * T1;          // out0 floats
    const unsigned B = (unsigned)N * STEPS_C;     // out1 floats
    const unsigned C = (unsigned)N * (FRD * T1);  // out2 floats
    const unsigned total4 = (A + B + C) >> 2;
    const unsigned stride = gridDim.x * blockDim.x;

    for (unsigned c = blockIdx.x * blockDim.x + threadIdx.x; c < total4; c += stride) {
        const unsigned f = c << 2;
        float vv[4];
        if (f < A) {
            // out0: walk_nodes [wl][51] = gbase + nodes[t][wl]
            unsigned wl = f / (unsigned)T1;
            unsigned t  = f - wl * (unsigned)T1;
            unsigned gb = (wl / (unsigned)ORDER) * (unsigned)ORDER;
#pragma unroll
            for (int u = 0; u < 4; u++) {
                vv[u] = (float)(gb + (unsigned)nodes_ws[(size_t)t * N + wl]);
                t++;
                if (t == T1) { t = 0; wl++; gb = (wl / (unsigned)ORDER) * (unsigned)ORDER; }
            }
        } else if (f < A + B) {
            // out1: walk_edges [wl][50] = (gbase+cur_t)*16 + ee_t
            const unsigned idx = f - A;
            unsigned wl = idx / (unsigned)STEPS_C;
            unsigned t  = idx - wl * (unsigned)STEPS_C;
            unsigned gb = (wl / (unsigned)ORDER) * (unsigned)ORDER;
#pragma unroll
            for (int u = 0; u < 4; u++) {
                const unsigned cur = (unsigned)nodes_ws[(size_t)t * N + wl];
                const unsigned ei  = (unsigned)eidx_ws[(size_t)t * N + wl];
                vv[u] = (float)(((gb + cur) << 4) + ei);   // < 2^24, exact
                t++;
                if (t == STEPS_C) { t = 0; wl++; gb = (wl / (unsigned)ORDER) * (unsigned)ORDER; }
            }
        } else {
            // out2: walk_x [wl][j<15][t<51] = bit t of masks[j][wl]
            const unsigned idx = f - A - B;
            unsigned wl  = idx / (unsigned)(FRD * T1);
            unsigned rem = idx - wl * (unsigned)(FRD * T1);
            unsigned j   = rem / (unsigned)T1;
            unsigned t   = rem - j * (unsigned)T1;
#pragma unroll
            for (int u = 0; u < 4; u++) {
                const unsigned long long m = masks_ws[(size_t)j * N + wl];
                vv[u] = ((m >> t) & 1ull) ? 1.0f : 0.0f;
                t++;
                if (t == T1) { t = 0; j++; if (j == FRD) { j = 0; wl++; } }
            }
        }
        float4 v; v.x = vv[0]; v.y = vv[1]; v.z = vv[2]; v.w = vv[3];
        *reinterpret_cast<float4*>(out + f) = v;
    }
}

// ============================================================
// Fallback single-kernel path (round-6 kernel, verified) —
// used only if ws_size is too small for the compact buffers.
// ============================================================
#define BLOCK 256
#define WPB 32
#define BPG 16
#define NSTRS 52
#define MSTR 17
#define ABSTR 9

__global__ __launch_bounds__(256)
void walker_kernel(const int* __restrict__ adj_nodes,
                   const int* __restrict__ adj_bits,
                   const int* __restrict__ choices,
                   float* __restrict__ out, int N)
{
    __shared__ unsigned short g_adj[ORDER * DEG];
    __shared__ int g_bits[ORDER * ABSTR];
    __shared__ int choice_lds[STEPS_C * WPB];
    __shared__ unsigned short nodes_l[WPB * NSTRS];
    __shared__ unsigned char  eidx_l[WPB * NSTRS];
    __shared__ unsigned long long mask_lds[WPB * MSTR];

    const int tid   = threadIdx.x;
    const int lane  = tid & 63;
    const int r     = tid & 7;
    const int g     = tid >> 3;
    const int graph = blockIdx.x >> 4;
    const int lb    = blockIdx.x & (BPG - 1);
    const int gbase = graph * ORDER;
    const int lstart = lb * WPB + g;
    const bool act  = (lstart < ORDER);
    const int wbaseN = gbase + lb * WPB;

    float* out0 = out;
    float* out1 = out + (size_t)N * T1;
    float* out2 = out1 + (size_t)N * STEPS_C;

    {
        const int2* src = reinterpret_cast<const int2*>(adj_nodes + (size_t)gbase * DEG);
        unsigned* dst = reinterpret_cast<unsigned*>(g_adj);
        for (int c = tid; c < ORDER * DEG / 2; c += BLOCK) {
            const int2 v = src[c];
            dst[c] = (unsigned)(v.x - gbase) | ((unsigned)(v.y - gbase) << 16);
        }
        const int4* srcb = reinterpret_cast<const int4*>(adj_bits + (size_t)gbase * NI);
        for (int c = tid; c < ORDER * NI / 4; c += BLOCK) {
            const int4 v = srcb[c];
            const int row = c >> 1;
            const int qb  = (c & 1) << 2;
            g_bits[row * ABSTR + qb + 0] = v.x;
            g_bits[row * ABSTR + qb + 1] = v.y;
            g_bits[row * ABSTR + qb + 2] = v.z;
            g_bits[row * ABSTR + qb + 3] = v.w;
        }
        for (int c = tid; c < STEPS_C * WPB; c += BLOCK) {
            const int t  = c >> 5;
            const int gg = c & (WPB - 1);
            int src_i = wbaseN + gg;
            if (src_i >= N) src_i = N - 1;
            choice_lds[c] = choices[(size_t)t * N + src_i];
        }
    }
    __syncthreads();

    unsigned long long idm = 0ull;
    unsigned long long adm = 0ull;

    if (act) {
        int wsel = (r == 7) ? lstart : 0;
        int cur  = lstart;
        int prev = -1;

        if (r == 0) nodes_l[g * NSTRS] = (unsigned short)lstart;

        for (int t = 0; t < STEPS_C; t++) {
            const int ch = choice_lds[t * WPB + g];
            const int e = ch & (DEG - 1);
            int r15 = ch % (DEG - 1); if (r15 < 0) r15 += (DEG - 1);
            const int e2 = (e + 1 + r15) & (DEG - 1);
            const int n1 = g_adj[cur * DEG + e];
            const int n2 = g_adj[cur * DEG + e2];
            const bool bt = (t >= 1) && (n1 == prev);
            const int nn = bt ? n2 : n1;
            const int ee = bt ? e2 : e;
            const unsigned q  = (unsigned)nn / 63u;
            const unsigned rr = (unsigned)nn - q * 63u;
            const unsigned long long bitpos = 1ull << (t + 1);
            const bool vk = (r + t) >= (WIN - 1);
            if (vk && (wsel == nn)) idm |= bitpos;
            const int word = g_bits[wsel * ABSTR + q];
            const unsigned s = rr > 31u ? 31u : rr;
            if (vk && (r < 7) && ((word >> s) & 1)) adm |= bitpos;
            const int up = __shfl(wsel, (lane & ~7) | ((r < 7) ? (r + 1) : 7));
            wsel = (r == 7) ? nn : up;
            prev = cur;
            cur  = nn;
            if (r == 0) nodes_l[g * NSTRS + t + 1] = (unsigned short)nn;
            if (r == 1) eidx_l[g * NSTRS + t]      = (unsigned char)ee;
        }
        mask_lds[g * MSTR + r] = idm;
        if (r < 7) mask_lds[g * MSTR + 8 + r] = adm;
    }
    __syncthreads();

    int nvalid = ORDER - lb * WPB;
    if (nvalid > WPB) nvalid = WPB;

    {
        float* dst = out0 + (size_t)wbaseN * T1;
        const unsigned nch = (unsigned)(nvalid * T1) >> 2;
        for (unsigned c = tid; c < nch; c += BLOCK) {
            const unsigned f0 = c << 2;
            float vv[4];
#pragma unroll
            for (int u = 0; u < 4; u++) {
                const unsigned idx = f0 + u;
                const unsigned wl = idx / (unsigned)T1;
                const unsigned t  = idx - wl * (unsigned)T1;
                vv[u] = (float)(gbase + (int)nodes_l[wl * NSTRS + t]);
            }
            float4 v; v.x = vv[0]; v.y = vv[1]; v.z = vv[2]; v.w = vv[3];
            *reinterpret_cast<float4*>(dst + f0) = v;
        }
    }
    {
        float* dst = out1 + (size_t)wbaseN * STEPS_C;
        const unsigned nch = (unsigned)(nvalid * STEPS_C) >> 2;
        for (unsigned c = tid; c < nch; c += BLOCK) {
            const unsigned f0 = c << 2;
            float vv[4];
#pragma unroll
            for (int u = 0; u < 4; u++) {
                const unsigned idx = f0 + u;
                const unsigned wl = idx / (unsigned)STEPS_C;
                const unsigned t  = idx - wl * (unsigned)STEPS_C;
                const int cur = (int)nodes_l[wl * NSTRS + t];
                const int ei  = (int)eidx_l[wl * NSTRS + t];
                vv[u] = (float)(((gbase + cur) << 4) + ei);
            }
            float4 v; v.x = vv[0]; v.y = vv[1]; v.z = vv[2]; v.w = vv[3];
            *reinterpret_cast<float4*>(dst + f0) = v;
        }
    }
    {
        float* dst = out2 + (size_t)wbaseN * (FRD * T1);
        const unsigned nch = (unsigned)(nvalid * (FRD * T1)) >> 2;
        for (unsigned c = tid; c < nch; c += BLOCK) {
            const unsigned f0 = c << 2;
            unsigned uu = f0 / (unsigned)T1;
            unsigned t  = f0 - uu * (unsigned)T1;
            unsigned wl = uu / (unsigned)FRD;
            unsigned j  = uu - wl * (unsigned)FRD;
            float vv[4];
#pragma unroll
            for (int u = 0; u < 4; u++) {
                const unsigned long long m = mask_lds[wl * MSTR + j];
                vv[u] = ((m >> t) & 1ull) ? 1.0f : 0.0f;
                t++;
                if (t == T1) { t = 0; j++; if (j == FRD) { j = 0; wl++; } }
            }
            float4 v; v.x = vv[0]; v.y = vv[1]; v.z = vv[2]; v.w = vv[3];
            *reinterpret_cast<float4*>(dst + f0) = v;
        }
    }
}

extern "C" void kernel_launch(void* const* d_in, const int* in_sizes, int n_in,
                              void* d_out, int out_size, void* d_ws, size_t ws_size,
                              hipStream_t stream) {
    const int N = in_sizes[3];               // 50000
    const int num_graphs = N / ORDER;        // 100

    const size_t masks_bytes = (size_t)15 * N * 8;
    const size_t nodes_bytes = (size_t)T1 * N * 2;
    const size_t eidx_bytes  = (size_t)STEPS_C * N;
    const size_t need = masks_bytes + nodes_bytes + eidx_bytes;   // 13.6 MB

    if (ws_size >= need) {
        unsigned long long* masks_ws = (unsigned long long*)d_ws;
        unsigned short* nodes_ws = (unsigned short*)((char*)d_ws + masks_bytes);
        unsigned char*  eidx_ws  = (unsigned char*)((char*)d_ws + masks_bytes + nodes_bytes);

        walk_kernel<<<num_graphs * 2, 256, 0, stream>>>(
            (const int*)d_in[0], (const int*)d_in[4], (const int*)d_in[5],
            masks_ws, nodes_ws, eidx_ws, N);

        expand_kernel<<<2048, 256, 0, stream>>>(
            masks_ws, nodes_ws, eidx_ws, (float*)d_out, N);
    } else {
        walker_kernel<<<num_graphs * BPG, BLOCK, 0, stream>>>(
            (const int*)d_in[0], (const int*)d_in[4], (const int*)d_in[5],
            (float*)d_out, N);
    }
}

// Round 8
// 67.635 us; speedup vs baseline: 1.2055x; 1.1404x over previous
//
#include <hip/hip_runtime.h>
#include <stdint.h>

#define WIN 8
#define DEG 16
#define ORDER 500
#define STEPS_C 50
#define T1 51          // STEPS+1
#define FRD 15         // feature rows = 2*WIN-1
#define NI 8           // adj_bits words per node
#define EW 16          // walkers per expand block

// ============================================================
// Two-kernel path. ws layout (SoA, coalesced in both kernels):
//   masks u64[15][N]  | nodes u16[51][N] | eidx u8[50][N]
// ============================================================

__global__ __launch_bounds__(128)
void walk_kernel(const int* __restrict__ adj_nodes,
                 const int* __restrict__ adj_bits,
                 const int* __restrict__ choices,
                 unsigned long long* __restrict__ masks_ws,  // [15][N]
                 unsigned short* __restrict__ nodes_ws,      // [51][N]
                 unsigned char* __restrict__ eidx_ws,        // [50][N]
                 int N)
{
    __shared__ unsigned short g_adj[ORDER * DEG];   // 16000 B (local ids)
    __shared__ int g_bits[ORDER * NI];              // 16000 B (banks uniform)

    const int tid   = threadIdx.x;
    const int graph = blockIdx.x >> 2;        // 4 blocks per graph
    const int lb    = blockIdx.x & 3;
    const int gbase = graph * ORDER;
    const int lstart = lb * 125 + tid;        // local walker id
    const bool act  = (tid < 125);
    const int wi    = gbase + lstart;
    const int wild  = act ? wi : gbase;       // safe load index

    // ---- stage graph tables into LDS (coalesced) ----
    {
        const int4* src = reinterpret_cast<const int4*>(adj_nodes + (size_t)gbase * DEG);
        unsigned* dst = reinterpret_cast<unsigned*>(g_adj);
        for (int c = tid; c < ORDER * DEG / 4; c += 128) {
            const int4 v = src[c];
            dst[2 * c + 0] = (unsigned)(v.x - gbase) | ((unsigned)(v.y - gbase) << 16);
            dst[2 * c + 1] = (unsigned)(v.z - gbase) | ((unsigned)(v.w - gbase) << 16);
        }
        int4* db = reinterpret_cast<int4*>(g_bits);
        const int4* sb = reinterpret_cast<const int4*>(adj_bits + (size_t)gbase * NI);
        for (int c = tid; c < ORDER * NI / 4; c += 128) db[c] = sb[c];
    }
    __syncthreads();

    int w[WIN];
    unsigned long long idm[WIN];
    unsigned long long adm[WIN - 1];
#pragma unroll
    for (int k = 0; k < WIN; k++) { w[k] = 0; idm[k] = 0ull; }
#pragma unroll
    for (int k = 0; k < WIN - 1; k++) adm[k] = 0ull;
    w[7] = act ? lstart : 0;

    if (act) nodes_ws[wi] = (unsigned short)lstart;   // row t=0

    // depth-8 rolling register prefetch of choices (coalesced, named regs)
    int c0 = choices[wild];
    int c1 = choices[(size_t)1 * N + wild];
    int c2 = choices[(size_t)2 * N + wild];
    int c3 = choices[(size_t)3 * N + wild];
    int c4 = choices[(size_t)4 * N + wild];
    int c5 = choices[(size_t)5 * N + wild];
    int c6 = choices[(size_t)6 * N + wild];
    int c7 = choices[(size_t)7 * N + wild];

    for (int t = 0; t < STEPS_C; t++) {
        const int ch = c0;
        c0 = c1; c1 = c2; c2 = c3; c3 = c4; c4 = c5; c5 = c6; c6 = c7;
        c7 = (t + 8 < STEPS_C) ? choices[(size_t)(t + 8) * N + wild] : 0;

        // deg==16 pow2: floored mod == AND (valid for negatives)
        const int e = ch & (DEG - 1);
        int r15 = ch % (DEG - 1); if (r15 < 0) r15 += (DEG - 1);
        const int e2 = (e + 1 + r15) & (DEG - 1);

        const int cur = w[7];
        const int n1 = g_adj[cur * DEG + e];
        const int n2 = g_adj[cur * DEG + e2];

        const bool bt = (t >= 1) && (n1 == w[6]);
        const int nn = bt ? n2 : n1;        // local id
        const int ee = bt ? e2 : e;         // edge index [0,16)

        // cid == local id directly (node_id closed form)
        const unsigned q  = (unsigned)nn / 63u;
        const unsigned rr = (unsigned)nn - q * 63u;
        const unsigned s  = rr > 31u ? 31u : rr;    // int32 saturating shift
        const unsigned long long bitpos = 1ull << (t + 1);

#pragma unroll
        for (int k = 0; k < WIN; k++) {
            const bool vk = (k + t) >= (WIN - 1);
            if (vk && (w[k] == nn)) idm[k] |= bitpos;
        }
#pragma unroll
        for (int k = 0; k < WIN - 1; k++) {
            const bool vk = (k + t) >= (WIN - 1);
            const int word = g_bits[w[k] * NI + q];
            if (vk && ((word >> s) & 1)) adm[k] |= bitpos;
        }

#pragma unroll
        for (int k = 0; k < WIN - 1; k++) w[k] = w[k + 1];
        w[7] = nn;

        if (act) {
            nodes_ws[(size_t)(t + 1) * N + wi] = (unsigned short)nn;
            eidx_ws[(size_t)t * N + wi]        = (unsigned char)ee;
        }
    }

    if (act) {
#pragma unroll
        for (int k = 0; k < WIN; k++)
            masks_ws[(size_t)k * N + wi] = idm[k];
#pragma unroll
        for (int k = 0; k < WIN - 1; k++)
            masks_ws[(size_t)(8 + k) * N + wi] = adm[k];
    }
}

__global__ __launch_bounds__(256)
void expand_kernel(const unsigned long long* __restrict__ masks_ws,
                   const unsigned short* __restrict__ nodes_ws,
                   const unsigned char* __restrict__ eidx_ws,
                   float* __restrict__ out, int N)
{
    __shared__ unsigned long long m_l[EW][16];    // [wl][j<15], pad 16
    __shared__ unsigned short     n_l[EW][52];    // [wl][t<51]
    __shared__ unsigned char      e_l[EW][52];    // [wl][t<50]
    __shared__ int                gb_l[EW];

    const int tid   = threadIdx.x;
    const int wbase = blockIdx.x * EW;

    // ---- stage this block's 16 walkers into LDS ----
    for (int c = tid; c < FRD * EW; c += 256) {           // 240
        const int k = c >> 4, wl = c & (EW - 1);
        m_l[wl][k] = masks_ws[(size_t)k * N + wbase + wl];
    }
    for (int c = tid; c < T1 * EW; c += 256) {            // 816
        const int t = c >> 4, wl = c & (EW - 1);
        n_l[wl][t] = nodes_ws[(size_t)t * N + wbase + wl];
    }
    for (int c = tid; c < STEPS_C * EW; c += 256) {       // 800
        const int t = c >> 4, wl = c & (EW - 1);
        e_l[wl][t] = eidx_ws[(size_t)t * N + wbase + wl];
    }
    if (tid < EW) gb_l[tid] = ((wbase + tid) / ORDER) * ORDER;
    __syncthreads();

    // ---- out0: walk_nodes, EW*51 = 816 floats = 204 float4 ----
    {
        float* dst = out + (size_t)wbase * T1;
        for (int c = tid; c < (EW * T1) >> 2; c += 256) {
            const int f0 = c << 2;
            float vv[4];
#pragma unroll
            for (int u = 0; u < 4; u++) {
                const int idx = f0 + u;
                const int wl = idx / T1;
                const int t  = idx - wl * T1;
                vv[u] = (float)(gb_l[wl] + (int)n_l[wl][t]);
            }
            float4 v; v.x = vv[0]; v.y = vv[1]; v.z = vv[2]; v.w = vv[3];
            *reinterpret_cast<float4*>(dst + f0) = v;
        }
    }
    // ---- out1: walk_edges, EW*50 = 800 floats = 200 float4 ----
    {
        float* dst = out + (size_t)N * T1 + (size_t)wbase * STEPS_C;
        for (int c = tid; c < (EW * STEPS_C) >> 2; c += 256) {
            const int f0 = c << 2;
            float vv[4];
#pragma unroll
            for (int u = 0; u < 4; u++) {
                const int idx = f0 + u;
                const int wl = idx / STEPS_C;
                const int t  = idx - wl * STEPS_C;
                const int cur = (int)n_l[wl][t];
                const int ei  = (int)e_l[wl][t];
                vv[u] = (float)(((gb_l[wl] + cur) << 4) + ei);   // < 2^24, exact
            }
            float4 v; v.x = vv[0]; v.y = vv[1]; v.z = vv[2]; v.w = vv[3];
            *reinterpret_cast<float4*>(dst + f0) = v;
        }
    }
    // ---- out2: walk_x, EW*765 = 12240 floats = 3060 float4 ----
    {
        float* dst = out + (size_t)N * (T1 + STEPS_C) + (size_t)wbase * (FRD * T1);
        for (int c = tid; c < (EW * FRD * T1) >> 2; c += 256) {
            const int f0 = c << 2;
            int wl  = f0 / (FRD * T1);
            int rem = f0 - wl * (FRD * T1);
            int j   = rem / T1;
            int t   = rem - j * T1;
            float vv[4];
#pragma unroll
            for (int u = 0; u < 4; u++) {
                vv[u] = ((m_l[wl][j] >> t) & 1ull) ? 1.0f : 0.0f;
                t++;
                if (t == T1) { t = 0; j++; if (j == FRD) { j = 0; wl++; } }
            }
            float4 v; v.x = vv[0]; v.y = vv[1]; v.z = vv[2]; v.w = vv[3];
            *reinterpret_cast<float4*>(dst + f0) = v;
        }
    }
}

// ============================================================
// Fallback single-kernel path (round-6 kernel, verified) —
// used only if ws_size is too small for the compact buffers.
// ============================================================
#define BLOCK 256
#define WPB 32
#define BPG 16
#define NSTRS 52
#define MSTR 17
#define ABSTR 9

__global__ __launch_bounds__(256)
void walker_kernel(const int* __restrict__ adj_nodes,
                   const int* __restrict__ adj_bits,
                   const int* __restrict__ choices,
                   float* __restrict__ out, int N)
{
    __shared__ unsigned short g_adj[ORDER * DEG];
    __shared__ int g_bits[ORDER * ABSTR];
    __shared__ int choice_lds[STEPS_C * WPB];
    __shared__ unsigned short nodes_l[WPB * NSTRS];
    __shared__ unsigned char  eidx_l[WPB * NSTRS];
    __shared__ unsigned long long mask_lds[WPB * MSTR];

    const int tid   = threadIdx.x;
    const int lane  = tid & 63;
    const int r     = tid & 7;
    const int g     = tid >> 3;
    const int graph = blockIdx.x >> 4;
    const int lb    = blockIdx.x & (BPG - 1);
    const int gbase = graph * ORDER;
    const int lstart = lb * WPB + g;
    const bool act  = (lstart < ORDER);
    const int wbaseN = gbase + lb * WPB;

    float* out0 = out;
    float* out1 = out + (size_t)N * T1;
    float* out2 = out1 + (size_t)N * STEPS_C;

    {
        const int2* src = reinterpret_cast<const int2*>(adj_nodes + (size_t)gbase * DEG);
        unsigned* dst = reinterpret_cast<unsigned*>(g_adj);
        for (int c = tid; c < ORDER * DEG / 2; c += BLOCK) {
            const int2 v = src[c];
            dst[c] = (unsigned)(v.x - gbase) | ((unsigned)(v.y - gbase) << 16);
        }
        const int4* srcb = reinterpret_cast<const int4*>(adj_bits + (size_t)gbase * NI);
        for (int c = tid; c < ORDER * NI / 4; c += BLOCK) {
            const int4 v = srcb[c];
            const int row = c >> 1;
            const int qb  = (c & 1) << 2;
            g_bits[row * ABSTR + qb + 0] = v.x;
            g_bits[row * ABSTR + qb + 1] = v.y;
            g_bits[row * ABSTR + qb + 2] = v.z;
            g_bits[row * ABSTR + qb + 3] = v.w;
        }
        for (int c = tid; c < STEPS_C * WPB; c += BLOCK) {
            const int t  = c >> 5;
            const int gg = c & (WPB - 1);
            int src_i = wbaseN + gg;
            if (src_i >= N) src_i = N - 1;
            choice_lds[c] = choices[(size_t)t * N + src_i];
        }
    }
    __syncthreads();

    unsigned long long idm = 0ull;
    unsigned long long adm = 0ull;

    if (act) {
        int wsel = (r == 7) ? lstart : 0;
        int cur  = lstart;
        int prev = -1;

        if (r == 0) nodes_l[g * NSTRS] = (unsigned short)lstart;

        for (int t = 0; t < STEPS_C; t++) {
            const int ch = choice_lds[t * WPB + g];
            const int e = ch & (DEG - 1);
            int r15 = ch % (DEG - 1); if (r15 < 0) r15 += (DEG - 1);
            const int e2 = (e + 1 + r15) & (DEG - 1);
            const int n1 = g_adj[cur * DEG + e];
            const int n2 = g_adj[cur * DEG + e2];
            const bool bt = (t >= 1) && (n1 == prev);
            const int nn = bt ? n2 : n1;
            const int ee = bt ? e2 : e;
            const unsigned q  = (unsigned)nn / 63u;
            const unsigned rr = (unsigned)nn - q * 63u;
            const unsigned long long bitpos = 1ull << (t + 1);
            const bool vk = (r + t) >= (WIN - 1);
            if (vk && (wsel == nn)) idm |= bitpos;
            const int word = g_bits[wsel * ABSTR + q];
            const unsigned s = rr > 31u ? 31u : rr;
            if (vk && (r < 7) && ((word >> s) & 1)) adm |= bitpos;
            const int up = __shfl(wsel, (lane & ~7) | ((r < 7) ? (r + 1) : 7));
            wsel = (r == 7) ? nn : up;
            prev = cur;
            cur  = nn;
            if (r == 0) nodes_l[g * NSTRS + t + 1] = (unsigned short)nn;
            if (r == 1) eidx_l[g * NSTRS + t]      = (unsigned char)ee;
        }
        mask_lds[g * MSTR + r] = idm;
        if (r < 7) mask_lds[g * MSTR + 8 + r] = adm;
    }
    __syncthreads();

    int nvalid = ORDER - lb * WPB;
    if (nvalid > WPB) nvalid = WPB;

    {
        float* dst = out0 + (size_t)wbaseN * T1;
        const unsigned nch = (unsigned)(nvalid * T1) >> 2;
        for (unsigned c = tid; c < nch; c += BLOCK) {
            const unsigned f0 = c << 2;
            float vv[4];
#pragma unroll
            for (int u = 0; u < 4; u++) {
                const unsigned idx = f0 + u;
                const unsigned wl = idx / (unsigned)T1;
                const unsigned t  = idx - wl * (unsigned)T1;
                vv[u] = (float)(gbase + (int)nodes_l[wl * NSTRS + t]);
            }
            float4 v; v.x = vv[0]; v.y = vv[1]; v.z = vv[2]; v.w = vv[3];
            *reinterpret_cast<float4*>(dst + f0) = v;
        }
    }
    {
        float* dst = out1 + (size_t)wbaseN * STEPS_C;
        const unsigned nch = (unsigned)(nvalid * STEPS_C) >> 2;
        for (unsigned c = tid; c < nch; c += BLOCK) {
            const unsigned f0 = c << 2;
            float vv[4];
#pragma unroll
            for (int u = 0; u < 4; u++) {
                const unsigned idx = f0 + u;
                const unsigned wl = idx / (unsigned)STEPS_C;
                const unsigned t  = idx - wl * (unsigned)STEPS_C;
                const int cur = (int)nodes_l[wl * NSTRS + t];
                const int ei  = (int)eidx_l[wl * NSTRS + t];
                vv[u] = (float)(((gbase + cur) << 4) + ei);
            }
            float4 v; v.x = vv[0]; v.y = vv[1]; v.z = vv[2]; v.w = vv[3];
            *reinterpret_cast<float4*>(dst + f0) = v;
        }
    }
    {
        float* dst = out2 + (size_t)wbaseN * (FRD * T1);
        const unsigned nch = (unsigned)(nvalid * (FRD * T1)) >> 2;
        for (unsigned c = tid; c < nch; c += BLOCK) {
            const unsigned f0 = c << 2;
            unsigned uu = f0 / (unsigned)T1;
            unsigned t  = f0 - uu * (unsigned)T1;
            unsigned wl = uu / (unsigned)FRD;
            unsigned j  = uu - wl * (unsigned)FRD;
            float vv[4];
#pragma unroll
            for (int u = 0; u < 4; u++) {
                const unsigned long long m = mask_lds[wl * MSTR + j];
                vv[u] = ((m >> t) & 1ull) ? 1.0f : 0.0f;
                t++;
                if (t == T1) { t = 0; j++; if (j == FRD) { j = 0; wl++; } }
            }
            float4 v; v.x = vv[0]; v.y = vv[1]; v.z = vv[2]; v.w = vv[3];
            *reinterpret_cast<float4*>(dst + f0) = v;
        }
    }
}

extern "C" void kernel_launch(void* const* d_in, const int* in_sizes, int n_in,
                              void* d_out, int out_size, void* d_ws, size_t ws_size,
                              hipStream_t stream) {
    const int N = in_sizes[3];               // 50000
    const int num_graphs = N / ORDER;        // 100

    const size_t masks_bytes = (size_t)15 * N * 8;
    const size_t nodes_bytes = (size_t)T1 * N * 2;
    const size_t eidx_bytes  = (size_t)STEPS_C * N;
    const size_t need = masks_bytes + nodes_bytes + eidx_bytes;   // 13.6 MB

    if (ws_size >= need) {
        unsigned long long* masks_ws = (unsigned long long*)d_ws;
        unsigned short* nodes_ws = (unsigned short*)((char*)d_ws + masks_bytes);
        unsigned char*  eidx_ws  = (unsigned char*)((char*)d_ws + masks_bytes + nodes_bytes);

        walk_kernel<<<num_graphs * 4, 128, 0, stream>>>(
            (const int*)d_in[0], (const int*)d_in[4], (const int*)d_in[5],
            masks_ws, nodes_ws, eidx_ws, N);

        expand_kernel<<<N / EW, 256, 0, stream>>>(
            masks_ws, nodes_ws, eidx_ws, (float*)d_out, N);
    } else {
        walker_kernel<<<num_graphs * BPG, BLOCK, 0, stream>>>(
            (const int*)d_in[0], (const int*)d_in[4], (const int*)d_in[5],
            (float*)d_out, N);
    }
}

// Round 9
// 64.894 us; speedup vs baseline: 1.2564x; 1.0422x over previous
//
#include <hip/hip_runtime.h>
#include <stdint.h>

#define WIN 8
#define DEG 16
#define ORDER 500
#define STEPS_C 50
#define T1 51          // STEPS+1
#define FRD 15         // feature rows = 2*WIN-1
#define NI 8           // adj_bits words per node
#define EW 16          // walkers per expand block

// ============================================================
// Two-kernel path. ws layout (SoA, coalesced in both kernels):
//   masks u64[15][N]  | nodes u16[51][N] | eidx u8[50][N]
// ============================================================

__global__ __launch_bounds__(128)
void walk_kernel(const int* __restrict__ adj_nodes,
                 const int* __restrict__ adj_bits,
                 const int* __restrict__ choices,
                 unsigned long long* __restrict__ masks_ws,  // [15][N]
                 unsigned short* __restrict__ nodes_ws,      // [51][N]
                 unsigned char* __restrict__ eidx_ws,        // [50][N]
                 int N)
{
    __shared__ unsigned short g_adj[ORDER * DEG];   // 16000 B (local ids)
    __shared__ int g_bits[ORDER * NI];              // 16000 B (banks uniform)

    const int tid   = threadIdx.x;
    const int graph = blockIdx.x >> 2;        // 4 blocks per graph
    const int lb    = blockIdx.x & 3;
    const int gbase = graph * ORDER;
    const int lstart = lb * 125 + tid;        // local walker id
    const bool act  = (tid < 125);
    const int wi    = gbase + lstart;
    const int wild  = act ? wi : gbase;       // safe load index

    // ---- stage graph tables into LDS (coalesced) ----
    {
        const int4* src = reinterpret_cast<const int4*>(adj_nodes + (size_t)gbase * DEG);
        unsigned* dst = reinterpret_cast<unsigned*>(g_adj);
        for (int c = tid; c < ORDER * DEG / 4; c += 128) {
            const int4 v = src[c];
            dst[2 * c + 0] = (unsigned)(v.x - gbase) | ((unsigned)(v.y - gbase) << 16);
            dst[2 * c + 1] = (unsigned)(v.z - gbase) | ((unsigned)(v.w - gbase) << 16);
        }
        int4* db = reinterpret_cast<int4*>(g_bits);
        const int4* sb = reinterpret_cast<const int4*>(adj_bits + (size_t)gbase * NI);
        for (int c = tid; c < ORDER * NI / 4; c += 128) db[c] = sb[c];
    }
    __syncthreads();

    int w[WIN];
    unsigned long long idm[WIN];
    unsigned long long adm[WIN - 1];
#pragma unroll
    for (int k = 0; k < WIN; k++) { w[k] = 0; idm[k] = 0ull; }
#pragma unroll
    for (int k = 0; k < WIN - 1; k++) adm[k] = 0ull;
    w[7] = act ? lstart : 0;

    if (act) nodes_ws[wi] = (unsigned short)lstart;   // row t=0

    // depth-8 rolling register prefetch of choices (coalesced, named regs)
    int c0 = choices[wild];
    int c1 = choices[(size_t)1 * N + wild];
    int c2 = choices[(size_t)2 * N + wild];
    int c3 = choices[(size_t)3 * N + wild];
    int c4 = choices[(size_t)4 * N + wild];
    int c5 = choices[(size_t)5 * N + wild];
    int c6 = choices[(size_t)6 * N + wild];
    int c7 = choices[(size_t)7 * N + wild];

    for (int t = 0; t < STEPS_C; t++) {
        const int ch = c0;
        c0 = c1; c1 = c2; c2 = c3; c3 = c4; c4 = c5; c5 = c6; c6 = c7;
        c7 = (t + 8 < STEPS_C) ? choices[(size_t)(t + 8) * N + wild] : 0;

        // deg==16 pow2: floored mod == AND (valid for negatives)
        const int e = ch & (DEG - 1);
        int r15 = ch % (DEG - 1); if (r15 < 0) r15 += (DEG - 1);
        const int e2 = (e + 1 + r15) & (DEG - 1);

        const int cur = w[7];
        const int n1 = g_adj[cur * DEG + e];
        const int n2 = g_adj[cur * DEG + e2];

        const bool bt = (t >= 1) && (n1 == w[6]);
        const int nn = bt ? n2 : n1;        // local id
        const int ee = bt ? e2 : e;         // edge index [0,16)

        // cid == local id directly (node_id closed form)
        const unsigned q  = (unsigned)nn / 63u;
        const unsigned rr = (unsigned)nn - q * 63u;
        const unsigned s  = rr > 31u ? 31u : rr;    // int32 saturating shift
        const unsigned long long bitpos = 1ull << (t + 1);

#pragma unroll
        for (int k = 0; k < WIN; k++) {
            const bool vk = (k + t) >= (WIN - 1);
            if (vk && (w[k] == nn)) idm[k] |= bitpos;
        }
#pragma unroll
        for (int k = 0; k < WIN - 1; k++) {
            const bool vk = (k + t) >= (WIN - 1);
            const int word = g_bits[w[k] * NI + q];
            if (vk && ((word >> s) & 1)) adm[k] |= bitpos;
        }

#pragma unroll
        for (int k = 0; k < WIN - 1; k++) w[k] = w[k + 1];
        w[7] = nn;

        if (act) {
            nodes_ws[(size_t)(t + 1) * N + wi] = (unsigned short)nn;
            eidx_ws[(size_t)t * N + wi]        = (unsigned char)ee;
        }
    }

    if (act) {
#pragma unroll
        for (int k = 0; k < WIN; k++)
            masks_ws[(size_t)k * N + wi] = idm[k];
#pragma unroll
        for (int k = 0; k < WIN - 1; k++)
            masks_ws[(size_t)(8 + k) * N + wi] = adm[k];
    }
}

__global__ __launch_bounds__(256)
void expand_kernel(const unsigned long long* __restrict__ masks_ws,
                   const unsigned short* __restrict__ nodes_ws,
                   const unsigned char* __restrict__ eidx_ws,
                   float* __restrict__ out, int N)
{
    __shared__ unsigned long long m_l[EW][16];    // [wl][j<15], pad 16
    __shared__ unsigned short     n_l[EW][52];    // [wl][t<51]
    __shared__ unsigned char      e_l[EW][52];    // [wl][t<50]
    __shared__ int                gb_l[EW];

    const int tid = threadIdx.x;

    // bijective XCD-aware tile swizzle (m204): XCD k gets a contiguous
    // tile range -> its L2 caches only ~1/8 of the compact ws buffer.
    const int nwg = gridDim.x;                    // 3125
    const int q8  = nwg >> 3, r8 = nwg & 7;
    const int xcd = blockIdx.x & 7, ord = blockIdx.x >> 3;
    const int tile = (xcd < r8 ? xcd * (q8 + 1) : r8 * (q8 + 1) + (xcd - r8) * q8) + ord;
    const int wbase = tile * EW;

    // ---- stage this block's 16 walkers into LDS ----
    for (int c = tid; c < FRD * EW; c += 256) {           // 240
        const int k = c >> 4, wl = c & (EW - 1);
        m_l[wl][k] = masks_ws[(size_t)k * N + wbase + wl];
    }
    for (int c = tid; c < T1 * EW; c += 256) {            // 816
        const int t = c >> 4, wl = c & (EW - 1);
        n_l[wl][t] = nodes_ws[(size_t)t * N + wbase + wl];
    }
    for (int c = tid; c < STEPS_C * EW; c += 256) {       // 800
        const int t = c >> 4, wl = c & (EW - 1);
        e_l[wl][t] = eidx_ws[(size_t)t * N + wbase + wl];
    }
    if (tid < EW) gb_l[tid] = ((wbase + tid) / ORDER) * ORDER;
    __syncthreads();

    // ---- out0: walk_nodes, EW*51 = 816 floats = 204 float4 ----
    {
        float* dst = out + (size_t)wbase * T1;
        for (int c = tid; c < (EW * T1) >> 2; c += 256) {
            const int f0 = c << 2;
            float vv[4];
#pragma unroll
            for (int u = 0; u < 4; u++) {
                const int idx = f0 + u;
                const int wl = idx / T1;
                const int t  = idx - wl * T1;
                vv[u] = (float)(gb_l[wl] + (int)n_l[wl][t]);
            }
            float4 v; v.x = vv[0]; v.y = vv[1]; v.z = vv[2]; v.w = vv[3];
            *reinterpret_cast<float4*>(dst + f0) = v;
        }
    }
    // ---- out1: walk_edges, EW*50 = 800 floats = 200 float4 ----
    {
        float* dst = out + (size_t)N * T1 + (size_t)wbase * STEPS_C;
        for (int c = tid; c < (EW * STEPS_C) >> 2; c += 256) {
            const int f0 = c << 2;
            float vv[4];
#pragma unroll
            for (int u = 0; u < 4; u++) {
                const int idx = f0 + u;
                const int wl = idx / STEPS_C;
                const int t  = idx - wl * STEPS_C;
                const int cur = (int)n_l[wl][t];
                const int ei  = (int)e_l[wl][t];
                vv[u] = (float)(((gb_l[wl] + cur) << 4) + ei);   // < 2^24, exact
            }
            float4 v; v.x = vv[0]; v.y = vv[1]; v.z = vv[2]; v.w = vv[3];
            *reinterpret_cast<float4*>(dst + f0) = v;
        }
    }
    // ---- out2: walk_x, EW*765 = 12240 floats = 3060 float4 ----
    {
        float* dst = out + (size_t)N * (T1 + STEPS_C) + (size_t)wbase * (FRD * T1);
        for (int c = tid; c < (EW * FRD * T1) >> 2; c += 256) {
            const int f0 = c << 2;
            int wl  = f0 / (FRD * T1);
            int rem = f0 - wl * (FRD * T1);
            int j   = rem / T1;
            int t   = rem - j * T1;
            float vv[4];
#pragma unroll
            for (int u = 0; u < 4; u++) {
                vv[u] = ((m_l[wl][j] >> t) & 1ull) ? 1.0f : 0.0f;
                t++;
                if (t == T1) { t = 0; j++; if (j == FRD) { j = 0; wl++; } }
            }
            float4 v; v.x = vv[0]; v.y = vv[1]; v.z = vv[2]; v.w = vv[3];
            *reinterpret_cast<float4*>(dst + f0) = v;
        }
    }
}

// ============================================================
// Fallback single-kernel path (round-6 kernel, verified) —
// used only if ws_size is too small for the compact buffers.
// ============================================================
#define BLOCK 256
#define WPB 32
#define BPG 16
#define NSTRS 52
#define MSTR 17
#define ABSTR 9

__global__ __launch_bounds__(256)
void walker_kernel(const int* __restrict__ adj_nodes,
                   const int* __restrict__ adj_bits,
                   const int* __restrict__ choices,
                   float* __restrict__ out, int N)
{
    __shared__ unsigned short g_adj[ORDER * DEG];
    __shared__ int g_bits[ORDER * ABSTR];
    __shared__ int choice_lds[STEPS_C * WPB];
    __shared__ unsigned short nodes_l[WPB * NSTRS];
    __shared__ unsigned char  eidx_l[WPB * NSTRS];
    __shared__ unsigned long long mask_lds[WPB * MSTR];

    const int tid   = threadIdx.x;
    const int lane  = tid & 63;
    const int r     = tid & 7;
    const int g     = tid >> 3;
    const int graph = blockIdx.x >> 4;
    const int lb    = blockIdx.x & (BPG - 1);
    const int gbase = graph * ORDER;
    const int lstart = lb * WPB + g;
    const bool act  = (lstart < ORDER);
    const int wbaseN = gbase + lb * WPB;

    float* out0 = out;
    float* out1 = out + (size_t)N * T1;
    float* out2 = out1 + (size_t)N * STEPS_C;

    {
        const int2* src = reinterpret_cast<const int2*>(adj_nodes + (size_t)gbase * DEG);
        unsigned* dst = reinterpret_cast<unsigned*>(g_adj);
        for (int c = tid; c < ORDER * DEG / 2; c += BLOCK) {
            const int2 v = src[c];
            dst[c] = (unsigned)(v.x - gbase) | ((unsigned)(v.y - gbase) << 16);
        }
        const int4* srcb = reinterpret_cast<const int4*>(adj_bits + (size_t)gbase * NI);
        for (int c = tid; c < ORDER * NI / 4; c += BLOCK) {
            const int4 v = srcb[c];
            const int row = c >> 1;
            const int qb  = (c & 1) << 2;
            g_bits[row * ABSTR + qb + 0] = v.x;
            g_bits[row * ABSTR + qb + 1] = v.y;
            g_bits[row * ABSTR + qb + 2] = v.z;
            g_bits[row * ABSTR + qb + 3] = v.w;
        }
        for (int c = tid; c < STEPS_C * WPB; c += BLOCK) {
            const int t  = c >> 5;
            const int gg = c & (WPB - 1);
            int src_i = wbaseN + gg;
            if (src_i >= N) src_i = N - 1;
            choice_lds[c] = choices[(size_t)t * N + src_i];
        }
    }
    __syncthreads();

    unsigned long long idm = 0ull;
    unsigned long long adm = 0ull;

    if (act) {
        int wsel = (r == 7) ? lstart : 0;
        int cur  = lstart;
        int prev = -1;

        if (r == 0) nodes_l[g * NSTRS] = (unsigned short)lstart;

        for (int t = 0; t < STEPS_C; t++) {
            const int ch = choice_lds[t * WPB + g];
            const int e = ch & (DEG - 1);
            int r15 = ch % (DEG - 1); if (r15 < 0) r15 += (DEG - 1);
            const int e2 = (e + 1 + r15) & (DEG - 1);
            const int n1 = g_adj[cur * DEG + e];
            const int n2 = g_adj[cur * DEG + e2];
            const bool bt = (t >= 1) && (n1 == prev);
            const int nn = bt ? n2 : n1;
            const int ee = bt ? e2 : e;
            const unsigned q  = (unsigned)nn / 63u;
            const unsigned rr = (unsigned)nn - q * 63u;
            const unsigned long long bitpos = 1ull << (t + 1);
            const bool vk = (r + t) >= (WIN - 1);
            if (vk && (wsel == nn)) idm |= bitpos;
            const int word = g_bits[wsel * ABSTR + q];
            const unsigned s = rr > 31u ? 31u : rr;
            if (vk && (r < 7) && ((word >> s) & 1)) adm |= bitpos;
            const int up = __shfl(wsel, (lane & ~7) | ((r < 7) ? (r + 1) : 7));
            wsel = (r == 7) ? nn : up;
            prev = cur;
            cur  = nn;
            if (r == 0) nodes_l[g * NSTRS + t + 1] = (unsigned short)nn;
            if (r == 1) eidx_l[g * NSTRS + t]      = (unsigned char)ee;
        }
        mask_lds[g * MSTR + r] = idm;
        if (r < 7) mask_lds[g * MSTR + 8 + r] = adm;
    }
    __syncthreads();

    int nvalid = ORDER - lb * WPB;
    if (nvalid > WPB) nvalid = WPB;

    {
        float* dst = out0 + (size_t)wbaseN * T1;
        const unsigned nch = (unsigned)(nvalid * T1) >> 2;
        for (unsigned c = tid; c < nch; c += BLOCK) {
            const unsigned f0 = c << 2;
            float vv[4];
#pragma unroll
            for (int u = 0; u < 4; u++) {
                const unsigned idx = f0 + u;
                const unsigned wl = idx / (unsigned)T1;
                const unsigned t  = idx - wl * (unsigned)T1;
                vv[u] = (float)(gbase + (int)nodes_l[wl * NSTRS + t]);
            }
            float4 v; v.x = vv[0]; v.y = vv[1]; v.z = vv[2]; v.w = vv[3];
            *reinterpret_cast<float4*>(dst + f0) = v;
        }
    }
    {
        float* dst = out1 + (size_t)wbaseN * STEPS_C;
        const unsigned nch = (unsigned)(nvalid * STEPS_C) >> 2;
        for (unsigned c = tid; c < nch; c += BLOCK) {
            const unsigned f0 = c << 2;
            float vv[4];
#pragma unroll
            for (int u = 0; u < 4; u++) {
                const unsigned idx = f0 + u;
                const unsigned wl = idx / (unsigned)STEPS_C;
                const unsigned t  = idx - wl * (unsigned)STEPS_C;
                const int cur = (int)nodes_l[wl * NSTRS + t];
                const int ei  = (int)eidx_l[wl * NSTRS + t];
                vv[u] = (float)(((gbase + cur) << 4) + ei);
            }
            float4 v; v.x = vv[0]; v.y = vv[1]; v.z = vv[2]; v.w = vv[3];
            *reinterpret_cast<float4*>(dst + f0) = v;
        }
    }
    {
        float* dst = out2 + (size_t)wbaseN * (FRD * T1);
        const unsigned nch = (unsigned)(nvalid * (FRD * T1)) >> 2;
        for (unsigned c = tid; c < nch; c += BLOCK) {
            const unsigned f0 = c << 2;
            unsigned uu = f0 / (unsigned)T1;
            unsigned t  = f0 - uu * (unsigned)T1;
            unsigned wl = uu / (unsigned)FRD;
            unsigned j  = uu - wl * (unsigned)FRD;
            float vv[4];
#pragma unroll
            for (int u = 0; u < 4; u++) {
                const unsigned long long m = mask_lds[wl * MSTR + j];
                vv[u] = ((m >> t) & 1ull) ? 1.0f : 0.0f;
                t++;
                if (t == T1) { t = 0; j++; if (j == FRD) { j = 0; wl++; } }
            }
            float4 v; v.x = vv[0]; v.y = vv[1]; v.z = vv[2]; v.w = vv[3];
            *reinterpret_cast<float4*>(dst + f0) = v;
        }
    }
}

extern "C" void kernel_launch(void* const* d_in, const int* in_sizes, int n_in,
                              void* d_out, int out_size, void* d_ws, size_t ws_size,
                              hipStream_t stream) {
    const int N = in_sizes[3];               // 50000
    const int num_graphs = N / ORDER;        // 100

    const size_t masks_bytes = (size_t)15 * N * 8;
    const size_t nodes_bytes = (size_t)T1 * N * 2;
    const size_t eidx_bytes  = (size_t)STEPS_C * N;
    const size_t need = masks_bytes + nodes_bytes + eidx_bytes;   // 13.6 MB

    if (ws_size >= need) {
        unsigned long long* masks_ws = (unsigned long long*)d_ws;
        unsigned short* nodes_ws = (unsigned short*)((char*)d_ws + masks_bytes);
        unsigned char*  eidx_ws  = (unsigned char*)((char*)d_ws + masks_bytes + nodes_bytes);

        walk_kernel<<<num_graphs * 4, 128, 0, stream>>>(
            (const int*)d_in[0], (const int*)d_in[4], (const int*)d_in[5],
            masks_ws, nodes_ws, eidx_ws, N);

        expand_kernel<<<N / EW, 256, 0, stream>>>(
            masks_ws, nodes_ws, eidx_ws, (float*)d_out, N);
    } else {
        walker_kernel<<<num_graphs * BPG, BLOCK, 0, stream>>>(
            (const int*)d_in[0], (const int*)d_in[4], (const int*)d_in[5],
            (float*)d_out, N);
    }
}

// Round 10
// 60.559 us; speedup vs baseline: 1.3463x; 1.0716x over previous
//
#include <hip/hip_runtime.h>
#include <stdint.h>

#define WIN 8
#define DEG 16
#define ORDER 500
#define STEPS_C 50
#define T1 51          // STEPS+1
#define FRD 15         // feature rows = 2*WIN-1
#define NI 8           // adj_bits words per node
#define WPB 125        // walkers per block
#define BLOCK 256
#define MSTR 17        // mask row stride in u64 (odd -> conflict-free)
#define NSTR 52        // nodes/eidx row stride (elements)

// Fused kernel: each block walks 125 walkers (walker-per-thread) and then
// expands its own outputs. No workspace, no inter-kernel dependency.
//
// LDS time-union (51520 B -> 3 blocks/CU):
//   walk phase:   [0,16000) g_adj u16 | [16000,32000) g_bits int
//   expand phase: [0,17000) mask_l u64[125][17]   (tables dead by then)
//   both:         [32000,45000) nodes_l u16[125][52]
//                 [45000,51500) eidx_l u8[125][52]
__global__ __launch_bounds__(256)
void fused_kernel(const int* __restrict__ adj_nodes,
                  const int* __restrict__ adj_bits,
                  const int* __restrict__ choices,
                  float* __restrict__ out, int N)
{
    __shared__ unsigned long long smem[6440];   // 51520 B
    unsigned short* g_adj  = (unsigned short*)smem;
    int*            g_bits = (int*)((char*)smem + 16000);
    unsigned long long* mask_l = smem;          // overlays tables after walk
    unsigned short* nodes_l = (unsigned short*)((char*)smem + 32000);
    unsigned char*  eidx_l  = (unsigned char*)((char*)smem + 45000);

    const int tid = threadIdx.x;

    // bijective XCD swizzle (nwg=400: q8=50) -> same-graph blocks share an XCD
    const int nwg = gridDim.x;
    const int q8  = nwg >> 3;
    const int vb  = ((nwg & 7) == 0) ? ((blockIdx.x & 7) * q8 + (blockIdx.x >> 3))
                                     : blockIdx.x;

    const int graph  = vb >> 2;              // 4 blocks per graph
    const int lb     = vb & 3;
    const int gbase  = graph * ORDER;
    const int lstart = lb * WPB + tid;       // local walker id in graph
    const bool act   = (tid < WPB);
    const int wi     = gbase + lstart;
    const int wild   = act ? wi : gbase;     // safe load index
    const int wbase  = vb * WPB;             // first global walker of block

    // ---- stage graph tables into LDS (coalesced) ----
    {
        const int4* src = (const int4*)(adj_nodes + (size_t)gbase * DEG);
        unsigned* dst = (unsigned*)g_adj;
        for (int c = tid; c < ORDER * DEG / 4; c += BLOCK) {
            const int4 v = src[c];
            dst[2 * c + 0] = (unsigned)(v.x - gbase) | ((unsigned)(v.y - gbase) << 16);
            dst[2 * c + 1] = (unsigned)(v.z - gbase) | ((unsigned)(v.w - gbase) << 16);
        }
        int4* db = (int4*)g_bits;
        const int4* sb = (const int4*)(adj_bits + (size_t)gbase * NI);
        for (int c = tid; c < ORDER * NI / 4; c += BLOCK) db[c] = sb[c];
    }
    __syncthreads();

    // ---- walk phase (walker-per-thread; dataflow verified r7-r9) ----
    unsigned long long idm[WIN];
    unsigned long long adm[WIN - 1];
#pragma unroll
    for (int k = 0; k < WIN; k++) idm[k] = 0ull;
#pragma unroll
    for (int k = 0; k < WIN - 1; k++) adm[k] = 0ull;

    if (act) {
        int w[WIN];
#pragma unroll
        for (int k = 0; k < WIN; k++) w[k] = 0;
        w[7] = lstart;

        nodes_l[tid * NSTR] = (unsigned short)lstart;   // row t=0 (local id)

        // depth-8 rolling register prefetch of choices (coalesced, named regs)
        int c0 = choices[wild];
        int c1 = choices[(size_t)1 * N + wild];
        int c2 = choices[(size_t)2 * N + wild];
        int c3 = choices[(size_t)3 * N + wild];
        int c4 = choices[(size_t)4 * N + wild];
        int c5 = choices[(size_t)5 * N + wild];
        int c6 = choices[(size_t)6 * N + wild];
        int c7 = choices[(size_t)7 * N + wild];

        for (int t = 0; t < STEPS_C; t++) {
            const int ch = c0;
            c0 = c1; c1 = c2; c2 = c3; c3 = c4; c4 = c5; c5 = c6; c6 = c7;
            c7 = (t + 8 < STEPS_C) ? choices[(size_t)(t + 8) * N + wild] : 0;

            // deg==16 pow2: floored mod == AND (valid for negatives)
            const int e = ch & (DEG - 1);
            int r15 = ch % (DEG - 1); if (r15 < 0) r15 += (DEG - 1);
            const int e2 = (e + 1 + r15) & (DEG - 1);

            const int cur = w[7];
            const int n1 = g_adj[cur * DEG + e];
            const int n2 = g_adj[cur * DEG + e2];

            const bool bt = (t >= 1) && (n1 == w[6]);
            const int nn = bt ? n2 : n1;        // local id
            const int ee = bt ? e2 : e;         // edge index [0,16)

            // cid == local id directly (node_id closed form)
            const unsigned q  = (unsigned)nn / 63u;
            const unsigned rr = (unsigned)nn - q * 63u;
            const unsigned s  = rr > 31u ? 31u : rr;    // int32 saturating shift
            const unsigned long long bitpos = 1ull << (t + 1);

#pragma unroll
            for (int k = 0; k < WIN; k++) {
                const bool vk = (k + t) >= (WIN - 1);
                if (vk && (w[k] == nn)) idm[k] |= bitpos;
            }
#pragma unroll
            for (int k = 0; k < WIN - 1; k++) {
                const bool vk = (k + t) >= (WIN - 1);
                const int word = g_bits[w[k] * NI + q];
                if (vk && ((word >> s) & 1)) adm[k] |= bitpos;
            }

#pragma unroll
            for (int k = 0; k < WIN - 1; k++) w[k] = w[k + 1];
            w[7] = nn;

            nodes_l[tid * NSTR + t + 1] = (unsigned short)nn;
            eidx_l[tid * NSTR + t]      = (unsigned char)ee;
        }
    }

    // tables are dead from here; barrier, then overlay masks into region A
    __syncthreads();
    if (act) {
#pragma unroll
        for (int k = 0; k < WIN; k++)      mask_l[tid * MSTR + k]     = idm[k];
#pragma unroll
        for (int k = 0; k < WIN - 1; k++)  mask_l[tid * MSTR + 8 + k] = adm[k];
    }
    __syncthreads();

    // ---- expand phase: all 256 threads, aligned float4 streams ----

    // out0: walk_nodes [wl][51] = gbase + nodes_l[wl][t]   (125*51 = 6375 floats)
    {
        float* dst = out + (size_t)wbase * T1;
        const int count = WPB * T1;
        const int head = (4 - (int)((((uintptr_t)dst) >> 2) & 3)) & 3;
        for (int i = tid; i < head; i += BLOCK) {
            const int wl = i / T1, t = i - wl * T1;
            dst[i] = (float)(gbase + (int)nodes_l[wl * NSTR + t]);
        }
        const int n4 = (count - head) >> 2;
        for (int c = tid; c < n4; c += BLOCK) {
            const int f0 = head + (c << 2);
            int wl = f0 / T1, t = f0 - wl * T1;
            float vv[4];
#pragma unroll
            for (int u = 0; u < 4; u++) {
                vv[u] = (float)(gbase + (int)nodes_l[wl * NSTR + t]);
                t++; if (t == T1) { t = 0; wl++; }
            }
            float4 v; v.x = vv[0]; v.y = vv[1]; v.z = vv[2]; v.w = vv[3];
            *reinterpret_cast<float4*>(dst + f0) = v;
        }
        const int done = head + (n4 << 2);
        for (int i = done + tid; i < count; i += BLOCK) {
            const int wl = i / T1, t = i - wl * T1;
            dst[i] = (float)(gbase + (int)nodes_l[wl * NSTR + t]);
        }
    }

    // out1: walk_edges [wl][50] = ((gbase+cur)<<4)+eidx   (125*50 = 6250 floats)
    {
        float* dst = out + (size_t)N * T1 + (size_t)wbase * STEPS_C;
        const int count = WPB * STEPS_C;
        const int head = (4 - (int)((((uintptr_t)dst) >> 2) & 3)) & 3;
        for (int i = tid; i < head; i += BLOCK) {
            const int wl = i / STEPS_C, t = i - wl * STEPS_C;
            dst[i] = (float)((((gbase + (int)nodes_l[wl * NSTR + t])) << 4)
                             + (int)eidx_l[wl * NSTR + t]);
        }
        const int n4 = (count - head) >> 2;
        for (int c = tid; c < n4; c += BLOCK) {
            const int f0 = head + (c << 2);
            int wl = f0 / STEPS_C, t = f0 - wl * STEPS_C;
            float vv[4];
#pragma unroll
            for (int u = 0; u < 4; u++) {
                vv[u] = (float)((((gbase + (int)nodes_l[wl * NSTR + t])) << 4)
                                + (int)eidx_l[wl * NSTR + t]);   // < 2^24, exact
                t++; if (t == STEPS_C) { t = 0; wl++; }
            }
            float4 v; v.x = vv[0]; v.y = vv[1]; v.z = vv[2]; v.w = vv[3];
            *reinterpret_cast<float4*>(dst + f0) = v;
        }
        const int done = head + (n4 << 2);
        for (int i = done + tid; i < count; i += BLOCK) {
            const int wl = i / STEPS_C, t = i - wl * STEPS_C;
            dst[i] = (float)((((gbase + (int)nodes_l[wl * NSTR + t])) << 4)
                             + (int)eidx_l[wl * NSTR + t]);
        }
    }

    // out2: walk_x [wl][j<15][t<51] = bit t of mask_l[wl][j]  (125*765 = 95625 floats)
    {
        float* dst = out + (size_t)N * (T1 + STEPS_C) + (size_t)wbase * (FRD * T1);
        const int count = WPB * FRD * T1;
        const int head = (4 - (int)((((uintptr_t)dst) >> 2) & 3)) & 3;
        for (int i = tid; i < head; i += BLOCK) {
            const int wl = i / (FRD * T1), rem = i - wl * (FRD * T1);
            const int j = rem / T1, t = rem - j * T1;
            dst[i] = ((mask_l[wl * MSTR + j] >> t) & 1ull) ? 1.0f : 0.0f;
        }
        const int n4 = (count - head) >> 2;
        for (int c = tid; c < n4; c += BLOCK) {
            const int f0 = head + (c << 2);
            int wl = f0 / (FRD * T1), rem = f0 - wl * (FRD * T1);
            int j = rem / T1, t = rem - j * T1;
            float vv[4];
#pragma unroll
            for (int u = 0; u < 4; u++) {
                vv[u] = ((mask_l[wl * MSTR + j] >> t) & 1ull) ? 1.0f : 0.0f;
                t++;
                if (t == T1) { t = 0; j++; if (j == FRD) { j = 0; wl++; } }
            }
            float4 v; v.x = vv[0]; v.y = vv[1]; v.z = vv[2]; v.w = vv[3];
            *reinterpret_cast<float4*>(dst + f0) = v;
        }
        const int done = head + (n4 << 2);
        for (int i = done + tid; i < count; i += BLOCK) {
            const int wl = i / (FRD * T1), rem = i - wl * (FRD * T1);
            const int j = rem / T1, t = rem - j * T1;
            dst[i] = ((mask_l[wl * MSTR + j] >> t) & 1ull) ? 1.0f : 0.0f;
        }
    }
}

extern "C" void kernel_launch(void* const* d_in, const int* in_sizes, int n_in,
                              void* d_out, int out_size, void* d_ws, size_t ws_size,
                              hipStream_t stream) {
    const int N = in_sizes[3];               // 50000
    const int num_graphs = N / ORDER;        // 100
    const int grid = num_graphs * 4;         // 400 blocks, 125 walkers each

    fused_kernel<<<grid, BLOCK, 0, stream>>>(
        (const int*)d_in[0], (const int*)d_in[4], (const int*)d_in[5],
        (float*)d_out, N);
}